// Round 2
// baseline (1231.522 us; speedup 1.0000x reference)
//
#include <hip/hip_runtime.h>
#include <hip/hip_bf16.h>

#define T_TOK 8192
#define DIM   1024
#define HID   4096
#define NE    8
#define RCAP  (T_TOK * 2 + 256)

typedef unsigned short u16;
typedef unsigned int   u32;
typedef float  f32x4 __attribute__((ext_vector_type(4)));
typedef __bf16 bf16x8 __attribute__((ext_vector_type(8)));

__device__ __forceinline__ u16 f2bf(float f) {
    u32 u = __builtin_bit_cast(u32, f);
    return (u16)((u + 0x7FFFu + ((u >> 16) & 1u)) >> 16);
}

#define GLOAD_LDS16(g, l) \
    __builtin_amdgcn_global_load_lds((const __attribute__((address_space(1))) u32*)(g), \
                                     (__attribute__((address_space(3))) u32*)(l), 16, 0, 0)

// ---------------- router: one wave per token ----------------
__global__ __launch_bounds__(256) void router_kernel(
    const float* __restrict__ x, const float* __restrict__ gw,
    int* __restrict__ tok_e, float* __restrict__ tok_w, int* __restrict__ cnt)
{
    int wid  = threadIdx.x >> 6;
    int lane = threadIdx.x & 63;
    int t = blockIdx.x * 4 + wid;

    const float4* xp = (const float4*)(x + (size_t)t * DIM);
    float4 xv[4];
    #pragma unroll
    for (int c = 0; c < 4; ++c) xv[c] = xp[c * 64 + lane];

    float r[NE];
    #pragma unroll
    for (int e = 0; e < NE; ++e) {
        const float4* gp = (const float4*)(gw + e * DIM);
        float acc = 0.f;
        #pragma unroll
        for (int c = 0; c < 4; ++c) {
            float4 g = gp[c * 64 + lane];
            acc += xv[c].x * g.x + xv[c].y * g.y + xv[c].z * g.z + xv[c].w * g.w;
        }
        r[e] = acc;
    }
    #pragma unroll
    for (int s = 1; s < 64; s <<= 1) {
        #pragma unroll
        for (int e = 0; e < NE; ++e) r[e] += __shfl_xor(r[e], s);
    }
    if (lane == 0) {
        int e0 = 0; float l0 = r[0];
        #pragma unroll
        for (int e = 1; e < NE; ++e) if (r[e] > l0) { l0 = r[e]; e0 = e; }
        int e1 = -1; float l1 = -3e38f;
        #pragma unroll
        for (int e = 0; e < NE; ++e) if (e != e0 && r[e] > l1) { l1 = r[e]; e1 = e; }
        float d  = __expf(l1 - l0);          // <= 1
        float w0 = 1.f / (1.f + d);
        float w1 = d * w0;
        tok_e[t * 2]     = e0;  tok_e[t * 2 + 1] = e1;
        tok_w[t * 2]     = w0;  tok_w[t * 2 + 1] = w1;
        atomicAdd(&cnt[e0], 1);
        atomicAdd(&cnt[e1], 1);
    }
}

// ---------------- prefix sum over 8 counts ----------------
__global__ void prefix_kernel(const int* __restrict__ cnt, int* __restrict__ base)
{
    if (threadIdx.x == 0) {
        int s = 0;
        for (int e = 0; e < NE; ++e) { base[e] = s; s += cnt[e]; }
    }
}

// ---------------- scatter rows + gather x -> bf16 A1 ----------------
__global__ __launch_bounds__(256) void scatter_kernel(
    const float* __restrict__ x, const int* __restrict__ tok_e, const float* __restrict__ tok_w,
    const int* __restrict__ base, int* __restrict__ cursor,
    int* __restrict__ rowmap, float* __restrict__ roww, u16* __restrict__ A1)
{
    __shared__ int srow[2];
    int t = blockIdx.x;
    if (threadIdx.x == 0) {
        #pragma unroll
        for (int k = 0; k < 2; ++k) {
            int e   = tok_e[t * 2 + k];
            int pos = atomicAdd(&cursor[e], 1);
            int row = base[e] + pos;
            rowmap[row] = t;
            roww[row]   = tok_w[t * 2 + k];
            srow[k] = row;
        }
    }
    __syncthreads();
    int i = threadIdx.x;
    float4 xv = ((const float4*)(x + (size_t)t * DIM))[i];
    u32 p0 = (u32)f2bf(xv.x) | ((u32)f2bf(xv.y) << 16);
    u32 p1 = (u32)f2bf(xv.z) | ((u32)f2bf(xv.w) << 16);
    #pragma unroll
    for (int k = 0; k < 2; ++k) {
        u32* dst = (u32*)(A1 + (size_t)srow[k] * DIM + i * 4);
        dst[0] = p0; dst[1] = p1;
    }
}

// ---------------- fp32 -> bf16 weight conversion ----------------
__global__ __launch_bounds__(256) void convw_kernel(
    const float* __restrict__ W1, const float* __restrict__ W2,
    u16* __restrict__ W1b, u16* __restrict__ W2b)
{
    const size_t n4 = (size_t)NE * HID * DIM / 4;   // float4s per tensor
    size_t stride = (size_t)gridDim.x * blockDim.x;
    for (size_t i = blockIdx.x * (size_t)blockDim.x + threadIdx.x; i < 2 * n4; i += stride) {
        const float* src = (i < n4) ? W1 : W2;
        u16*         dst = (i < n4) ? W1b : W2b;
        size_t j = (i < n4) ? i : i - n4;
        float4 v = ((const float4*)src)[j];
        u32 p0 = (u32)f2bf(v.x) | ((u32)f2bf(v.y) << 16);
        u32 p1 = (u32)f2bf(v.z) | ((u32)f2bf(v.w) << 16);
        ((u32*)dst)[j * 2]     = p0;
        ((u32*)dst)[j * 2 + 1] = p1;
    }
}

// ---------------- grouped GEMM: 256x256 tile, BK=64, 8 waves (2Mx4N) ----------------
// Double-buffered 128 KB LDS; stage-early + counted s_waitcnt vmcnt(8);
// raw s_barrier (no __syncthreads drain). XCD-chunked block swizzle.
template<int KDIM, int NDIM, bool IS_G2>
__global__ __launch_bounds__(512, 2) void moe_gemm(
    const u16* __restrict__ A, const u16* __restrict__ B,
    const float* __restrict__ bias,
    u16* __restrict__ Hout, float* __restrict__ Yout,
    const int* __restrict__ rowmap, const float* __restrict__ roww,
    const int* __restrict__ cnt, const int* __restrict__ base)
{
    constexpr int NT  = NDIM / 256;
    constexpr int MT  = 32;               // worst case 8192 rows on one expert
    constexpr int NKT = KDIM / 64;

    // XCD swizzle: grid is a multiple of 8; chunk work so each XCD owns a
    // contiguous range (here: exactly one expert per XCD).
    int nwg = NE * MT * NT;
    int bid = blockIdx.x;
    int wid = (bid & 7) * (nwg >> 3) + (bid >> 3);
    int e   = wid / (MT * NT);
    int rem = wid % (MT * NT);
    int nt  = rem / MT;                   // mt fastest: consecutive work shares B panel
    int mt  = rem % MT;
    int ce  = cnt[e];
    if (mt * 256 >= ce) return;
    int m0 = base[e] + mt * 256;
    int n0 = nt * 256;
    const u16* Bp = B + (size_t)e * NDIM * KDIM;

    __shared__ u16 As[2][256 * 64];       // 64 KB
    __shared__ u16 Bs[2][256 * 64];       // 64 KB

    int tid  = threadIdx.x;
    int lane = tid & 63;
    int w    = tid >> 6;
    int wr   = w >> 2;                    // 0..1 -> M half
    int wc   = w & 3;                     // 0..3 -> N quarter

    // chunk layout for staging: chunk c (0..31) = 8 rows x 64 cols = 1 KB,
    // filled by one wave's 64 lanes x 16 B. LDS base is wave-uniform.
#define STAGE(bufi, kt_) do {                                                   \
        _Pragma("unroll")                                                       \
        for (int j_ = 0; j_ < 4; ++j_) {                                        \
            int c_   = j_ * 8 + w;                                              \
            int row_ = c_ * 8 + (lane >> 3);                                    \
            int col_ = (lane & 7) * 8 + (kt_) * 64;                             \
            GLOAD_LDS16(A  + (size_t)(m0 + row_) * KDIM + col_, As[bufi] + c_ * 512); \
            GLOAD_LDS16(Bp + (size_t)(n0 + row_) * KDIM + col_, Bs[bufi] + c_ * 512); \
        }                                                                       \
    } while (0)

    f32x4 acc[8][4];
    #pragma unroll
    for (int m = 0; m < 8; ++m)
        #pragma unroll
        for (int n = 0; n < 4; ++n)
            #pragma unroll
            for (int i = 0; i < 4; ++i) acc[m][n][i] = 0.f;

    STAGE(0, 0);                          // 8 loads in flight
    STAGE(1, 1);                          // 16 in flight

    for (int kt = 0; kt < NKT; ++kt) {
        // wait for tile kt's 8 loads; leave tile kt+1's 8 flying (counted vmcnt)
        if (kt == NKT - 1) asm volatile("s_waitcnt vmcnt(0)" ::: "memory");
        else               asm volatile("s_waitcnt vmcnt(8)" ::: "memory");
        __builtin_amdgcn_s_barrier();
        __builtin_amdgcn_sched_barrier(0);

        int b = kt & 1;
        #pragma unroll
        for (int kk = 0; kk < 2; ++kk) {
            bf16x8 af[8], bfr[4];
            #pragma unroll
            for (int m = 0; m < 8; ++m)
                af[m] = *(const bf16x8*)(As[b] + (wr * 128 + m * 16 + (lane & 15)) * 64 + kk * 32 + (lane >> 4) * 8);
            #pragma unroll
            for (int n = 0; n < 4; ++n)
                bfr[n] = *(const bf16x8*)(Bs[b] + (wc * 64 + n * 16 + (lane & 15)) * 64 + kk * 32 + (lane >> 4) * 8);
            #pragma unroll
            for (int m = 0; m < 8; ++m)
                #pragma unroll
                for (int n = 0; n < 4; ++n)
                    acc[m][n] = __builtin_amdgcn_mfma_f32_16x16x32_bf16(af[m], bfr[n], acc[m][n], 0, 0, 0);
        }

        __builtin_amdgcn_sched_barrier(0);
        __builtin_amdgcn_s_barrier();     // all waves done reading buf b
        __builtin_amdgcn_sched_barrier(0);
        if (kt + 2 < NKT) STAGE(b, kt + 2);   // refill the buffer just consumed
    }

    // epilogue: C/D layout col = lane&15, row = (lane>>4)*4 + reg
    #pragma unroll
    for (int m = 0; m < 8; ++m) {
        #pragma unroll
        for (int j = 0; j < 4; ++j) {
            int rr   = wr * 128 + m * 16 + (lane >> 4) * 4 + j;
            int rloc = mt * 256 + rr;
            if (rloc < ce) {
                if (!IS_G2) {
                    u16* hp = Hout + (size_t)(m0 + rr) * NDIM;
                    #pragma unroll
                    for (int n = 0; n < 4; ++n) {
                        int gcol = n0 + wc * 64 + n * 16 + (lane & 15);
                        float v = acc[m][n][j] + bias[e * NDIM + gcol];
                        v = v > 0.f ? v : 0.f;
                        hp[gcol] = f2bf(v);
                    }
                } else {
                    int   tok = rowmap[m0 + rr];
                    float wgt = roww[m0 + rr];
                    float* op = Yout + (size_t)tok * DIM;
                    #pragma unroll
                    for (int n = 0; n < 4; ++n) {
                        int gcol = n0 + wc * 64 + n * 16 + (lane & 15);
                        float v = acc[m][n][j] + bias[e * NDIM + gcol];
                        atomicAdd(op + gcol, wgt * v);
                    }
                }
            }
        }
    }
#undef STAGE
}

extern "C" void kernel_launch(void* const* d_in, const int* in_sizes, int n_in,
                              void* d_out, int out_size, void* d_ws, size_t ws_size,
                              hipStream_t stream) {
    const float* xs = (const float*)d_in[0];
    const float* gw = (const float*)d_in[1];
    const float* W1 = (const float*)d_in[2];
    const float* b1 = (const float*)d_in[3];
    const float* W2 = (const float*)d_in[4];
    const float* b2 = (const float*)d_in[5];
    float* out = (float*)d_out;

    char* ws = (char*)d_ws;
    size_t off = 0;
    auto alloc = [&](size_t bytes) -> void* {
        off = (off + 255) & ~(size_t)255;
        void* p = ws + off;
        off += bytes;
        return p;
    };
    int*   ctrs   = (int*)alloc(64);            // cnt[8] + cursor[8]
    int*   cnt    = ctrs;
    int*   cursor = ctrs + 8;
    int*   base   = (int*)alloc(32);
    int*   tok_e  = (int*)alloc((size_t)T_TOK * 2 * 4);
    float* tok_w  = (float*)alloc((size_t)T_TOK * 2 * 4);
    int*   rowmap = (int*)alloc((size_t)RCAP * 4);
    float* roww   = (float*)alloc((size_t)RCAP * 4);
    u16*   A1     = (u16*)alloc((size_t)RCAP * DIM * 2);
    u16*   W1b    = (u16*)alloc((size_t)NE * HID * DIM * 2);
    u16*   W2b    = (u16*)alloc((size_t)NE * HID * DIM * 2);
    u16*   hbuf   = (u16*)alloc((size_t)RCAP * HID * 2);
    (void)ws_size; (void)in_sizes; (void)n_in; (void)out_size;

    hipMemsetAsync(out, 0, (size_t)T_TOK * DIM * sizeof(float), stream);
    hipMemsetAsync(ctrs, 0, 64, stream);

    router_kernel<<<T_TOK / 4, 256, 0, stream>>>(xs, gw, tok_e, tok_w, cnt);
    prefix_kernel<<<1, 64, 0, stream>>>(cnt, base);
    scatter_kernel<<<T_TOK, 256, 0, stream>>>(xs, tok_e, tok_w, base, cursor, rowmap, roww, A1);
    convw_kernel<<<2048, 256, 0, stream>>>(W1, W2, W1b, W2b);

    moe_gemm<DIM, HID, false><<<NE * 32 * (HID / 256), 512, 0, stream>>>(
        A1, W1b, b1, hbuf, nullptr, nullptr, nullptr, cnt, base);
    moe_gemm<HID, DIM, true><<<NE * 32 * (DIM / 256), 512, 0, stream>>>(
        hbuf, W2b, b2, nullptr, out, rowmap, roww, cnt, base);
}

// Round 3
// 1041.582 us; speedup vs baseline: 1.1824x; 1.1824x over previous
//
#include <hip/hip_runtime.h>
#include <hip/hip_bf16.h>

#define T_TOK 8192
#define DIM   1024
#define HID   4096
#define NE    8
#define RCAP  (T_TOK * 2 + 256)

typedef unsigned short u16;
typedef unsigned int   u32;
typedef float  f32x4 __attribute__((ext_vector_type(4)));
typedef __bf16 bf16x8 __attribute__((ext_vector_type(8)));

__device__ __forceinline__ u16 f2bf(float f) {
    u32 u = __builtin_bit_cast(u32, f);
    return (u16)((u + 0x7FFFu + ((u >> 16) & 1u)) >> 16);
}

#define GLOAD_LDS16(g, l) \
    __builtin_amdgcn_global_load_lds((const __attribute__((address_space(1))) u32*)(g), \
                                     (__attribute__((address_space(3))) u32*)(l), 16, 0, 0)

// ---------------- router: one wave per token ----------------
__global__ __launch_bounds__(256) void router_kernel(
    const float* __restrict__ x, const float* __restrict__ gw,
    int* __restrict__ tok_e, float* __restrict__ tok_w, int* __restrict__ cnt)
{
    int wid  = threadIdx.x >> 6;
    int lane = threadIdx.x & 63;
    int t = blockIdx.x * 4 + wid;

    const float4* xp = (const float4*)(x + (size_t)t * DIM);
    float4 xv[4];
    #pragma unroll
    for (int c = 0; c < 4; ++c) xv[c] = xp[c * 64 + lane];

    float r[NE];
    #pragma unroll
    for (int e = 0; e < NE; ++e) {
        const float4* gp = (const float4*)(gw + e * DIM);
        float acc = 0.f;
        #pragma unroll
        for (int c = 0; c < 4; ++c) {
            float4 g = gp[c * 64 + lane];
            acc += xv[c].x * g.x + xv[c].y * g.y + xv[c].z * g.z + xv[c].w * g.w;
        }
        r[e] = acc;
    }
    #pragma unroll
    for (int s = 1; s < 64; s <<= 1) {
        #pragma unroll
        for (int e = 0; e < NE; ++e) r[e] += __shfl_xor(r[e], s);
    }
    if (lane == 0) {
        int e0 = 0; float l0 = r[0];
        #pragma unroll
        for (int e = 1; e < NE; ++e) if (r[e] > l0) { l0 = r[e]; e0 = e; }
        int e1 = -1; float l1 = -3e38f;
        #pragma unroll
        for (int e = 0; e < NE; ++e) if (e != e0 && r[e] > l1) { l1 = r[e]; e1 = e; }
        float d  = __expf(l1 - l0);          // <= 1
        float w0 = 1.f / (1.f + d);
        float w1 = d * w0;
        tok_e[t * 2]     = e0;  tok_e[t * 2 + 1] = e1;
        tok_w[t * 2]     = w0;  tok_w[t * 2 + 1] = w1;
        atomicAdd(&cnt[e0], 1);
        atomicAdd(&cnt[e1], 1);
    }
}

// ---------------- prefix sum over 8 counts ----------------
__global__ void prefix_kernel(const int* __restrict__ cnt, int* __restrict__ base)
{
    if (threadIdx.x == 0) {
        int s = 0;
        for (int e = 0; e < NE; ++e) { base[e] = s; s += cnt[e]; }
    }
}

// ---------------- scatter rows + gather x -> bf16 A1 ----------------
__global__ __launch_bounds__(256) void scatter_kernel(
    const float* __restrict__ x, const int* __restrict__ tok_e, const float* __restrict__ tok_w,
    const int* __restrict__ base, int* __restrict__ cursor,
    int* __restrict__ rowmap, float* __restrict__ roww, u16* __restrict__ A1)
{
    __shared__ int srow[2];
    int t = blockIdx.x;
    if (threadIdx.x == 0) {
        #pragma unroll
        for (int k = 0; k < 2; ++k) {
            int e   = tok_e[t * 2 + k];
            int pos = atomicAdd(&cursor[e], 1);
            int row = base[e] + pos;
            rowmap[row] = t;
            roww[row]   = tok_w[t * 2 + k];
            srow[k] = row;
        }
    }
    __syncthreads();
    int i = threadIdx.x;
    float4 xv = ((const float4*)(x + (size_t)t * DIM))[i];
    u32 p0 = (u32)f2bf(xv.x) | ((u32)f2bf(xv.y) << 16);
    u32 p1 = (u32)f2bf(xv.z) | ((u32)f2bf(xv.w) << 16);
    #pragma unroll
    for (int k = 0; k < 2; ++k) {
        u32* dst = (u32*)(A1 + (size_t)srow[k] * DIM + i * 4);
        dst[0] = p0; dst[1] = p1;
    }
}

// ---------------- fp32 -> bf16 weight conversion ----------------
__global__ __launch_bounds__(256) void convw_kernel(
    const float* __restrict__ W1, const float* __restrict__ W2,
    u16* __restrict__ W1b, u16* __restrict__ W2b)
{
    const size_t n4 = (size_t)NE * HID * DIM / 4;   // float4s per tensor
    size_t stride = (size_t)gridDim.x * blockDim.x;
    for (size_t i = blockIdx.x * (size_t)blockDim.x + threadIdx.x; i < 2 * n4; i += stride) {
        const float* src = (i < n4) ? W1 : W2;
        u16*         dst = (i < n4) ? W1b : W2b;
        size_t j = (i < n4) ? i : i - n4;
        float4 v = ((const float4*)src)[j];
        u32 p0 = (u32)f2bf(v.x) | ((u32)f2bf(v.y) << 16);
        u32 p1 = (u32)f2bf(v.z) | ((u32)f2bf(v.w) << 16);
        ((u32*)dst)[j * 2]     = p0;
        ((u32*)dst)[j * 2 + 1] = p1;
    }
}

// ---------------- grouped GEMM: 256x256 tile, BK=32, 8 waves (2Mx4N) ----------------
// 4-buffer LDS ring (128 KB), prefetch depth 3, ONE barrier per K-tile,
// counted s_waitcnt vmcnt(8) (never 0 until the tail). 64B LDS rows are
// naturally bank-conflict-free for the b128 fragment reads (no swizzle needed).
template<int KDIM, int NDIM, bool IS_G2>
__global__ __launch_bounds__(512, 2) void moe_gemm(
    const u16* __restrict__ A, const u16* __restrict__ B,
    const float* __restrict__ bias,
    u16* __restrict__ Hout, float* __restrict__ Yout,
    const int* __restrict__ rowmap, const float* __restrict__ roww,
    const int* __restrict__ cnt, const int* __restrict__ base)
{
    constexpr int NKT = KDIM / 32;
    constexpr int NT  = NDIM / 256;
    constexpr int MT  = 32;               // worst case 8192 rows on one expert

    int nwg = NE * MT * NT;
    int bid = blockIdx.x;
    int wid = (bid & 7) * (nwg >> 3) + (bid >> 3);   // XCD-chunked swizzle
    int e   = wid / (MT * NT);
    int rem = wid % (MT * NT);
    int nt  = rem / MT;                   // mt fastest: consecutive work shares B panel
    int mt  = rem % MT;
    int ce  = cnt[e];
    if (mt * 256 >= ce) return;
    int m0 = base[e] + mt * 256;
    int n0 = nt * 256;
    const u16* Bp = B + (size_t)e * NDIM * KDIM;

    // 4 buffers x (A: 256x32 + B: 256x32) u16 = 4 x 32 KB = 128 KB
    __shared__ u16 lds[4 * 16384];

    int tid  = threadIdx.x;
    int lane = tid & 63;
    int w    = tid >> 6;
    int wr   = w >> 2;                    // 0..1 -> M half
    int wc   = w & 3;                     // 0..3 -> N quarter

    // ---- staging precompute: per K-tile each thread issues 4 x 16B loads.
    // Load q covers: q0=A rows 0..127, q1=A rows 128..255, q2=B low, q3=B high.
    // LDS dst (linear, wave-uniform base + lane*16): row = w*16 + lane/4,
    // col bytes = (lane&3)*16.
    int colel = (lane & 3) * 8;
    int srow  = w * 16 + (lane >> 2);     // 0..127
    const u16* aS0 = A  + (size_t)(m0 + srow)       * KDIM + colel;
    const u16* aS1 = A  + (size_t)(m0 + 128 + srow) * KDIM + colel;
    const u16* bS0 = Bp + (size_t)(n0 + srow)       * KDIM + colel;
    const u16* bS1 = Bp + (size_t)(n0 + 128 + srow) * KDIM + colel;
    u16* dA0 = lds + w * 512 + lane * 8;
    u16* dA1 = dA0 + 4096;
    u16* dB0 = dA0 + 8192;
    u16* dB1 = dA0 + 12288;

#define STAGE(kt_) do {                                   \
        int    bo_ = ((kt_) & 3) * 16384;                 \
        size_t ko_ = (size_t)(kt_) * 32;                  \
        GLOAD_LDS16(aS0 + ko_, dA0 + bo_);                \
        GLOAD_LDS16(aS1 + ko_, dA1 + bo_);                \
        GLOAD_LDS16(bS0 + ko_, dB0 + bo_);                \
        GLOAD_LDS16(bS1 + ko_, dB1 + bo_);                \
    } while (0)

    // ---- fragment-read bases (16x16x32 MFMA: lane reads row lane&15,
    // 8 elems at col (lane>>4)*8): u16 idx = row*32 + (lane>>4)*8.
    const u16* aRd = lds        + (wr * 128 + (lane & 15)) * 32 + (lane >> 4) * 8;
    const u16* bRd = lds + 8192 + (wc * 64  + (lane & 15)) * 32 + (lane >> 4) * 8;

    f32x4 acc[8][4];
    #pragma unroll
    for (int m = 0; m < 8; ++m)
        #pragma unroll
        for (int n = 0; n < 4; ++n)
            #pragma unroll
            for (int i = 0; i < 4; ++i) acc[m][n][i] = 0.f;

    STAGE(0); STAGE(1); STAGE(2);         // 12 loads in flight (3 tiles)

    for (int kt = 0; kt < NKT; ++kt) {
        // wait for tile kt's 4 loads; keep tiles kt+1, kt+2 (8 loads) flying
        if (kt + 2 < NKT)      asm volatile("s_waitcnt vmcnt(8)" ::: "memory");
        else if (kt + 1 < NKT) asm volatile("s_waitcnt vmcnt(4)" ::: "memory");
        else                   asm volatile("s_waitcnt vmcnt(0)" ::: "memory");
        __builtin_amdgcn_s_barrier();     // all waves' kt data landed; buf[kt+3 mod 4] free
        __builtin_amdgcn_sched_barrier(0);
        if (kt + 3 < NKT) STAGE(kt + 3);

        int bo = (kt & 3) * 16384;
        bf16x8 af[8], bv[4];
        #pragma unroll
        for (int m = 0; m < 8; ++m) af[m] = *(const bf16x8*)(aRd + bo + m * 512);
        #pragma unroll
        for (int n = 0; n < 4; ++n) bv[n] = *(const bf16x8*)(bRd + bo + n * 512);

        __builtin_amdgcn_s_setprio(1);
        #pragma unroll
        for (int m = 0; m < 8; ++m)
            #pragma unroll
            for (int n = 0; n < 4; ++n)
                acc[m][n] = __builtin_amdgcn_mfma_f32_16x16x32_bf16(af[m], bv[n], acc[m][n], 0, 0, 0);
        __builtin_amdgcn_s_setprio(0);
    }
#undef STAGE

    // epilogue: C/D layout col = lane&15, row = (lane>>4)*4 + reg
    #pragma unroll
    for (int m = 0; m < 8; ++m) {
        #pragma unroll
        for (int j = 0; j < 4; ++j) {
            int rr   = wr * 128 + m * 16 + (lane >> 4) * 4 + j;
            int rloc = mt * 256 + rr;
            if (rloc < ce) {
                if (!IS_G2) {
                    u16* hp = Hout + (size_t)(m0 + rr) * NDIM;
                    #pragma unroll
                    for (int n = 0; n < 4; ++n) {
                        int gcol = n0 + wc * 64 + n * 16 + (lane & 15);
                        float v = acc[m][n][j] + bias[e * NDIM + gcol];
                        v = v > 0.f ? v : 0.f;
                        hp[gcol] = f2bf(v);
                    }
                } else {
                    int   tok = rowmap[m0 + rr];
                    float wgt = roww[m0 + rr];
                    float* op = Yout + (size_t)tok * DIM;
                    #pragma unroll
                    for (int n = 0; n < 4; ++n) {
                        int gcol = n0 + wc * 64 + n * 16 + (lane & 15);
                        float v = acc[m][n][j] + bias[e * NDIM + gcol];
                        atomicAdd(op + gcol, wgt * v);
                    }
                }
            }
        }
    }
}

extern "C" void kernel_launch(void* const* d_in, const int* in_sizes, int n_in,
                              void* d_out, int out_size, void* d_ws, size_t ws_size,
                              hipStream_t stream) {
    const float* xs = (const float*)d_in[0];
    const float* gw = (const float*)d_in[1];
    const float* W1 = (const float*)d_in[2];
    const float* b1 = (const float*)d_in[3];
    const float* W2 = (const float*)d_in[4];
    const float* b2 = (const float*)d_in[5];
    float* out = (float*)d_out;

    char* ws = (char*)d_ws;
    size_t off = 0;
    auto alloc = [&](size_t bytes) -> void* {
        off = (off + 255) & ~(size_t)255;
        void* p = ws + off;
        off += bytes;
        return p;
    };
    int*   ctrs   = (int*)alloc(64);            // cnt[8] + cursor[8]
    int*   cnt    = ctrs;
    int*   cursor = ctrs + 8;
    int*   base   = (int*)alloc(32);
    int*   tok_e  = (int*)alloc((size_t)T_TOK * 2 * 4);
    float* tok_w  = (float*)alloc((size_t)T_TOK * 2 * 4);
    int*   rowmap = (int*)alloc((size_t)RCAP * 4);
    float* roww   = (float*)alloc((size_t)RCAP * 4);
    u16*   A1     = (u16*)alloc((size_t)RCAP * DIM * 2);
    u16*   W1b    = (u16*)alloc((size_t)NE * HID * DIM * 2);
    u16*   W2b    = (u16*)alloc((size_t)NE * HID * DIM * 2);
    u16*   hbuf   = (u16*)alloc((size_t)RCAP * HID * 2);
    (void)ws_size; (void)in_sizes; (void)n_in; (void)out_size;

    hipMemsetAsync(out, 0, (size_t)T_TOK * DIM * sizeof(float), stream);
    hipMemsetAsync(ctrs, 0, 64, stream);

    router_kernel<<<T_TOK / 4, 256, 0, stream>>>(xs, gw, tok_e, tok_w, cnt);
    prefix_kernel<<<1, 64, 0, stream>>>(cnt, base);
    scatter_kernel<<<T_TOK, 256, 0, stream>>>(xs, tok_e, tok_w, base, cursor, rowmap, roww, A1);
    convw_kernel<<<2048, 256, 0, stream>>>(W1, W2, W1b, W2b);

    moe_gemm<DIM, HID, false><<<NE * 32 * (HID / 256), 512, 0, stream>>>(
        A1, W1b, b1, hbuf, nullptr, nullptr, nullptr, cnt, base);
    moe_gemm<HID, DIM, true><<<NE * 32 * (DIM / 256), 512, 0, stream>>>(
        hbuf, W2b, b2, nullptr, out, rowmap, roww, cnt, base);
}

// Round 4
// 992.838 us; speedup vs baseline: 1.2404x; 1.0491x over previous
//
#include <hip/hip_runtime.h>
#include <hip/hip_bf16.h>

#define T_TOK 8192
#define DIM   1024
#define HID   4096
#define NE    8
#define RCAP  (T_TOK * 2 + 256)

typedef unsigned short u16;
typedef unsigned int   u32;
typedef float  f32x4 __attribute__((ext_vector_type(4)));
typedef __bf16 bf16x8 __attribute__((ext_vector_type(8)));

__device__ __forceinline__ u16 f2bf(float f) {
    u32 u = __builtin_bit_cast(u32, f);
    return (u16)((u + 0x7FFFu + ((u >> 16) & 1u)) >> 16);
}

#define GLOAD_LDS16(g, l) \
    __builtin_amdgcn_global_load_lds((const __attribute__((address_space(1))) u32*)(g), \
                                     (__attribute__((address_space(3))) u32*)(l), 16, 0, 0)

// ---------------- router: one wave per token ----------------
__global__ __launch_bounds__(256) void router_kernel(
    const float* __restrict__ x, const float* __restrict__ gw,
    int* __restrict__ tok_e, float* __restrict__ tok_w, int* __restrict__ cnt)
{
    int wid  = threadIdx.x >> 6;
    int lane = threadIdx.x & 63;
    int t = blockIdx.x * 4 + wid;

    const float4* xp = (const float4*)(x + (size_t)t * DIM);
    float4 xv[4];
    #pragma unroll
    for (int c = 0; c < 4; ++c) xv[c] = xp[c * 64 + lane];

    float r[NE];
    #pragma unroll
    for (int e = 0; e < NE; ++e) {
        const float4* gp = (const float4*)(gw + e * DIM);
        float acc = 0.f;
        #pragma unroll
        for (int c = 0; c < 4; ++c) {
            float4 g = gp[c * 64 + lane];
            acc += xv[c].x * g.x + xv[c].y * g.y + xv[c].z * g.z + xv[c].w * g.w;
        }
        r[e] = acc;
    }
    #pragma unroll
    for (int s = 1; s < 64; s <<= 1) {
        #pragma unroll
        for (int e = 0; e < NE; ++e) r[e] += __shfl_xor(r[e], s);
    }
    if (lane == 0) {
        int e0 = 0; float l0 = r[0];
        #pragma unroll
        for (int e = 1; e < NE; ++e) if (r[e] > l0) { l0 = r[e]; e0 = e; }
        int e1 = -1; float l1 = -3e38f;
        #pragma unroll
        for (int e = 0; e < NE; ++e) if (e != e0 && r[e] > l1) { l1 = r[e]; e1 = e; }
        float d  = __expf(l1 - l0);          // <= 1
        float w0 = 1.f / (1.f + d);
        float w1 = d * w0;
        tok_e[t * 2]     = e0;  tok_e[t * 2 + 1] = e1;
        tok_w[t * 2]     = w0;  tok_w[t * 2 + 1] = w1;
        atomicAdd(&cnt[e0], 1);
        atomicAdd(&cnt[e1], 1);
    }
}

// ---------------- prefix sum + work-queue build ----------------
// q item encode: (e<<16) | (ks<<12) | (nt<<8) | mt
__global__ void prefix_kernel(const int* __restrict__ cnt, int* __restrict__ base,
                              int* __restrict__ q1, int* __restrict__ q2,
                              int* __restrict__ qmeta)
{
    if (threadIdx.x == 0) {
        int s = 0;
        for (int e = 0; e < NE; ++e) { base[e] = s; s += cnt[e]; }
        int n1 = 0, n2 = 0;
        for (int e = 0; e < NE; ++e) {
            int mts = (cnt[e] + 255) >> 8;
            for (int nt = 0; nt < HID / 256; ++nt)
                for (int mt = 0; mt < mts; ++mt)
                    q1[n1++] = (e << 16) | (nt << 8) | mt;
            for (int ks = 0; ks < 2; ++ks)
                for (int nt = 0; nt < DIM / 256; ++nt)
                    for (int mt = 0; mt < mts; ++mt)
                        q2[n2++] = (e << 16) | (ks << 12) | (nt << 8) | mt;
        }
        qmeta[0] = n1; qmeta[1] = n2; qmeta[2] = 0; qmeta[3] = 0;
    }
}

// ---------------- scatter rows + gather x -> bf16 A1 ----------------
__global__ __launch_bounds__(256) void scatter_kernel(
    const float* __restrict__ x, const int* __restrict__ tok_e,
    const int* __restrict__ base, int* __restrict__ cursor,
    int* __restrict__ invrow, u16* __restrict__ A1)
{
    __shared__ int srow[2];
    int t = blockIdx.x;
    if (threadIdx.x == 0) {
        #pragma unroll
        for (int k = 0; k < 2; ++k) {
            int e   = tok_e[t * 2 + k];
            int pos = atomicAdd(&cursor[e], 1);
            int row = base[e] + pos;
            invrow[t * 2 + k] = row;
            srow[k] = row;
        }
    }
    __syncthreads();
    int i = threadIdx.x;
    float4 xv = ((const float4*)(x + (size_t)t * DIM))[i];
    u32 p0 = (u32)f2bf(xv.x) | ((u32)f2bf(xv.y) << 16);
    u32 p1 = (u32)f2bf(xv.z) | ((u32)f2bf(xv.w) << 16);
    #pragma unroll
    for (int k = 0; k < 2; ++k) {
        u32* dst = (u32*)(A1 + (size_t)srow[k] * DIM + i * 4);
        dst[0] = p0; dst[1] = p1;
    }
}

// ---------------- fp32 -> bf16 weight conversion ----------------
__global__ __launch_bounds__(256) void convw_kernel(
    const float* __restrict__ W1, const float* __restrict__ W2,
    u16* __restrict__ W1b, u16* __restrict__ W2b)
{
    const size_t n4 = (size_t)NE * HID * DIM / 4;
    size_t stride = (size_t)gridDim.x * blockDim.x;
    for (size_t i = blockIdx.x * (size_t)blockDim.x + threadIdx.x; i < 2 * n4; i += stride) {
        const float* src = (i < n4) ? W1 : W2;
        u16*         dst = (i < n4) ? W1b : W2b;
        size_t j = (i < n4) ? i : i - n4;
        float4 v = ((const float4*)src)[j];
        u32 p0 = (u32)f2bf(v.x) | ((u32)f2bf(v.y) << 16);
        u32 p1 = (u32)f2bf(v.z) | ((u32)f2bf(v.w) << 16);
        ((u32*)dst)[j * 2]     = p0;
        ((u32*)dst)[j * 2 + 1] = p1;
    }
}

// ---------------- persistent grouped GEMM ----------------
// 256x256 tile, BK=32, 8 waves (2Mx4N). 4-buffer LDS ring (128 KB), prefetch
// distance 3 K-tiles. Per K-tile: 2 phases of {ds_read ∥ stage ; barrier;
// lgkmcnt(0); setprio; 16 MFMA; setprio; barrier}; one counted vmcnt(8)/K-tile.
template<int KDIM, int NDIM, bool IS_G2>
__global__ __launch_bounds__(512, 2) void moe_gemm(
    const u16* __restrict__ A, const u16* __restrict__ B,
    const float* __restrict__ bias,
    u16* __restrict__ Hout, float* __restrict__ Y0, float* __restrict__ Y1,
    const int* __restrict__ cnt, const int* __restrict__ base,
    const int* __restrict__ queue, const int* __restrict__ qtot, int* __restrict__ qcur)
{
    constexpr int KLEN = IS_G2 ? (KDIM / 2) : KDIM;   // split-K=2 for GEMM2
    constexpr int NKT  = KLEN / 32;

    __shared__ u16 lds[4 * 16384];        // 4 ring slots x (A 256x32 + B 256x32)
    __shared__ int sitem;

    int tid  = threadIdx.x;
    int lane = tid & 63;
    int w    = tid >> 6;
    int wr   = w >> 2, wc = w & 3;

    // fragment-read offsets (u16 units), + slot*16384
    int aOff = (wr * 128 + (lane & 15)) * 32 + (lane >> 4) * 8;
    int bOff = 8192 + (wc * 64 + (lane & 15)) * 32 + (lane >> 4) * 8;

    // staging: slot s = w*64+lane (+512); row = s>>2, col16 = s&3
    int srow = w * 16 + (lane >> 2);      // 0..127
    int scol = (lane & 3) * 8;            // element col
    u16* dA0 = lds + (w * 64 + lane) * 8; // byte = slot*16 (wave-uniform base + lane*16)
    u16* dA1 = dA0 + 4096;                // +512 slots -> rows +128
    u16* dB0 = dA0 + 8192;
    u16* dB1 = dA0 + 12288;

    for (;;) {
        __syncthreads();                  // drains vm/lgkm + protects sitem & LDS reuse
        if (tid == 0) {
            int p = atomicAdd(qcur, 1);
            sitem = (p < *qtot) ? queue[p] : -1;
        }
        __syncthreads();
        int item = sitem;
        if (item < 0) break;

        int e  = item >> 16;
        int ks = (item >> 12) & 15;
        int nt = (item >> 8) & 15;
        int mt = item & 255;
        int ce = cnt[e];
        int m0 = base[e] + mt * 256;
        int n0 = nt * 256;
        int k0 = ks * KLEN;

        const u16* aS0 = A + (size_t)(m0 + srow) * KDIM + k0 + scol;
        const u16* aS1 = aS0 + (size_t)128 * KDIM;
        const u16* bS0 = B + (size_t)e * NDIM * KDIM + (size_t)(n0 + srow) * KDIM + k0 + scol;
        const u16* bS1 = bS0 + (size_t)128 * KDIM;

#define STAGE_A(kt_) do { int b_ = ((kt_) & 3) * 16384; size_t ko_ = (size_t)(kt_) * 32; \
        GLOAD_LDS16(aS0 + ko_, dA0 + b_); GLOAD_LDS16(aS1 + ko_, dA1 + b_); } while (0)
#define STAGE_B(kt_) do { int b_ = ((kt_) & 3) * 16384; size_t ko_ = (size_t)(kt_) * 32; \
        GLOAD_LDS16(bS0 + ko_, dB0 + b_); GLOAD_LDS16(bS1 + ko_, dB1 + b_); } while (0)

        f32x4 acc[8][4];
        #pragma unroll
        for (int m = 0; m < 8; ++m)
            #pragma unroll
            for (int n = 0; n < 4; ++n)
                #pragma unroll
                for (int i = 0; i < 4; ++i) acc[m][n][i] = 0.f;

        STAGE_A(0); STAGE_B(0); STAGE_A(1); STAGE_B(1); STAGE_A(2); STAGE_B(2);
        asm volatile("s_waitcnt vmcnt(8)" ::: "memory");   // tile0's 4 loads done
        __builtin_amdgcn_s_barrier();

        for (int kt = 0; kt < NKT; ++kt) {
            int bo = (kt & 3) * 16384;
            bf16x8 am[8], bn[4];
            // ---- phase 0: read m0-3 + all bn, stage next A-unit
            #pragma unroll
            for (int m = 0; m < 4; ++m) am[m] = *(const bf16x8*)(lds + bo + aOff + m * 512);
            #pragma unroll
            for (int n = 0; n < 4; ++n) bn[n] = *(const bf16x8*)(lds + bo + bOff + n * 512);
            if (kt + 3 < NKT) STAGE_A(kt + 3);
            __builtin_amdgcn_s_barrier();
            asm volatile("s_waitcnt lgkmcnt(0)" ::: "memory");
            __builtin_amdgcn_sched_barrier(0);
            __builtin_amdgcn_s_setprio(1);
            #pragma unroll
            for (int m = 0; m < 4; ++m)
                #pragma unroll
                for (int n = 0; n < 4; ++n)
                    acc[m][n] = __builtin_amdgcn_mfma_f32_16x16x32_bf16(am[m], bn[n], acc[m][n], 0, 0, 0);
            __builtin_amdgcn_s_setprio(0);
            __builtin_amdgcn_sched_barrier(0);
            __builtin_amdgcn_s_barrier();
            // ---- phase 1: read m4-7, stage next B-unit
            #pragma unroll
            for (int m = 4; m < 8; ++m) am[m] = *(const bf16x8*)(lds + bo + aOff + m * 512);
            if (kt + 3 < NKT) STAGE_B(kt + 3);
            __builtin_amdgcn_s_barrier();
            asm volatile("s_waitcnt lgkmcnt(0)" ::: "memory");
            __builtin_amdgcn_sched_barrier(0);
            __builtin_amdgcn_s_setprio(1);
            #pragma unroll
            for (int m = 4; m < 8; ++m)
                #pragma unroll
                for (int n = 0; n < 4; ++n)
                    acc[m][n] = __builtin_amdgcn_mfma_f32_16x16x32_bf16(am[m], bn[n], acc[m][n], 0, 0, 0);
            __builtin_amdgcn_s_setprio(0);
            __builtin_amdgcn_sched_barrier(0);
            // counted wait: ensure tile kt+1 landed; keep kt+2, kt+3 flying
            if (kt < NKT - 3)       asm volatile("s_waitcnt vmcnt(8)" ::: "memory");
            else if (kt == NKT - 3) asm volatile("s_waitcnt vmcnt(4)" ::: "memory");
            else                    asm volatile("s_waitcnt vmcnt(0)" ::: "memory");
            __builtin_amdgcn_s_barrier();   // closing barrier = next tile's opening
        }
#undef STAGE_A
#undef STAGE_B

        // epilogue: C/D layout col = lane&15, row = (lane>>4)*4 + reg
        #pragma unroll
        for (int m = 0; m < 8; ++m) {
            #pragma unroll
            for (int j = 0; j < 4; ++j) {
                int rr   = wr * 128 + m * 16 + (lane >> 4) * 4 + j;
                int rloc = mt * 256 + rr;
                if (rloc < ce) {
                    if (!IS_G2) {
                        u16* hp = Hout + (size_t)(m0 + rr) * NDIM;
                        #pragma unroll
                        for (int n = 0; n < 4; ++n) {
                            int gcol = n0 + wc * 64 + n * 16 + (lane & 15);
                            float v = acc[m][n][j] + bias[e * NDIM + gcol];
                            v = v > 0.f ? v : 0.f;
                            hp[gcol] = f2bf(v);
                        }
                    } else {
                        float* yp = (ks == 0 ? Y0 : Y1) + (size_t)(m0 + rr) * NDIM;
                        #pragma unroll
                        for (int n = 0; n < 4; ++n) {
                            int gcol = n0 + wc * 64 + n * 16 + (lane & 15);
                            float v = acc[m][n][j];
                            if (ks == 0) v += bias[e * NDIM + gcol];
                            yp[gcol] = v;
                        }
                    }
                }
            }
        }
        asm volatile("s_waitcnt vmcnt(0)" ::: "memory");   // drain stores: keep ledger sound
    }
}

// ---------------- combine: out[t] = w0*(Y0[r0]+Y1[r0]) + w1*(Y0[r1]+Y1[r1]) ----------------
__global__ __launch_bounds__(256) void combine_kernel(
    const float* __restrict__ Y0, const float* __restrict__ Y1,
    const int* __restrict__ invrow, const float* __restrict__ tok_w,
    float* __restrict__ out)
{
    int t  = blockIdx.x;
    int r0 = invrow[t * 2], r1 = invrow[t * 2 + 1];
    float w0 = tok_w[t * 2], w1 = tok_w[t * 2 + 1];
    int i = threadIdx.x;
    float4 a0 = ((const float4*)(Y0 + (size_t)r0 * DIM))[i];
    float4 b0 = ((const float4*)(Y1 + (size_t)r0 * DIM))[i];
    float4 a1 = ((const float4*)(Y0 + (size_t)r1 * DIM))[i];
    float4 b1 = ((const float4*)(Y1 + (size_t)r1 * DIM))[i];
    float4 o;
    o.x = w0 * (a0.x + b0.x) + w1 * (a1.x + b1.x);
    o.y = w0 * (a0.y + b0.y) + w1 * (a1.y + b1.y);
    o.z = w0 * (a0.z + b0.z) + w1 * (a1.z + b1.z);
    o.w = w0 * (a0.w + b0.w) + w1 * (a1.w + b1.w);
    ((float4*)(out + (size_t)t * DIM))[i] = o;
}

extern "C" void kernel_launch(void* const* d_in, const int* in_sizes, int n_in,
                              void* d_out, int out_size, void* d_ws, size_t ws_size,
                              hipStream_t stream) {
    const float* xs = (const float*)d_in[0];
    const float* gw = (const float*)d_in[1];
    const float* W1 = (const float*)d_in[2];
    const float* b1 = (const float*)d_in[3];
    const float* W2 = (const float*)d_in[4];
    const float* b2 = (const float*)d_in[5];
    float* out = (float*)d_out;

    char* ws = (char*)d_ws;
    size_t off = 0;
    auto alloc = [&](size_t bytes) -> void* {
        off = (off + 255) & ~(size_t)255;
        void* p = ws + off;
        off += bytes;
        return p;
    };
    int*   ctrs   = (int*)alloc(64);            // cnt[8] + cursor[8]
    int*   cnt    = ctrs;
    int*   cursor = ctrs + 8;
    int*   base   = (int*)alloc(32);
    int*   qmeta  = (int*)alloc(64);            // n1, n2, cur1, cur2
    int*   tok_e  = (int*)alloc((size_t)T_TOK * 2 * 4);
    float* tok_w  = (float*)alloc((size_t)T_TOK * 2 * 4);
    int*   invrow = (int*)alloc((size_t)T_TOK * 2 * 4);
    int*   q1     = (int*)alloc(2048 * 4);
    int*   q2     = (int*)alloc(1024 * 4);
    u16*   A1     = (u16*)alloc((size_t)RCAP * DIM * 2);       // 34 MB
    u16*   W1b    = (u16*)alloc((size_t)NE * HID * DIM * 2);   // 64 MB (contiguous after A1)
    u16*   W2b    = (u16*)alloc((size_t)NE * HID * DIM * 2);   // 64 MB
    u16*   hbuf   = (u16*)alloc((size_t)RCAP * HID * 2);       // 136 MB
    float* Ypart0 = (float*)alloc((size_t)T_TOK * 2 * DIM * 4);// 64 MB
    float* Ypart1 = (float*)A1;   // alias A1+W1b (both dead during GEMM2/combine)
    (void)ws_size; (void)in_sizes; (void)n_in; (void)out_size;

    hipMemsetAsync(ctrs, 0, 64, stream);

    router_kernel<<<T_TOK / 4, 256, 0, stream>>>(xs, gw, tok_e, tok_w, cnt);
    prefix_kernel<<<1, 64, 0, stream>>>(cnt, base, q1, q2, qmeta);
    scatter_kernel<<<T_TOK, 256, 0, stream>>>(xs, tok_e, base, cursor, invrow, A1);
    convw_kernel<<<2048, 256, 0, stream>>>(W1, W2, W1b, W2b);

    moe_gemm<DIM, HID, false><<<256, 512, 0, stream>>>(
        A1, W1b, b1, hbuf, nullptr, nullptr, cnt, base, q1, qmeta + 0, qmeta + 2);
    moe_gemm<HID, DIM, true><<<256, 512, 0, stream>>>(
        hbuf, W2b, b2, nullptr, Ypart0, Ypart1, cnt, base, q2, qmeta + 1, qmeta + 3);

    combine_kernel<<<T_TOK, 256, 0, stream>>>(Ypart0, Ypart1, invrow, tok_w, out);
}